// Round 3
// baseline (310.736 us; speedup 1.0000x reference)
//
#include <hip/hip_runtime.h>
#include <cstdint>

// Problem constants: B=2, L=2048, D=1024, H=16, DK=64
#define SEQ     2048
#define DMODEL  1024
#define NHEAD   16
#define DKH     64
#define NTOK    4096      // B*L
#define LDQKV   3072      // qkv buffer row stride (q|k|v)

typedef __bf16 bf16x8 __attribute__((ext_vector_type(8)));
typedef __bf16 bf16x4 __attribute__((ext_vector_type(4)));
typedef float  f32x4  __attribute__((ext_vector_type(4)));

#define MFMA_BF16(a, b, c) __builtin_amdgcn_mfma_f32_16x16x32_bf16((a), (b), (c), 0, 0, 0)

// async global->LDS copy, 16B per lane; LDS dest is wave-uniform base + lane*16
__device__ inline void async_copy16(const void* g, void* l) {
  __builtin_amdgcn_global_load_lds(
      reinterpret_cast<const __attribute__((address_space(1))) void*>(
          reinterpret_cast<uintptr_t>(g)),
      reinterpret_cast<__attribute__((address_space(3))) void*>(
          reinterpret_cast<uintptr_t>(l)),
      16, 0, 0);
}

__device__ inline bf16x4 cvt4(float4 v) {
  bf16x4 r;
  r[0] = (__bf16)v.x; r[1] = (__bf16)v.y; r[2] = (__bf16)v.z; r[3] = (__bf16)v.w;
  return r;
}

// ---------------- pack: fp32 -> bf16 casts + weight/bias concat ----------------
__global__ __launch_bounds__(256) void pack_kernel(
    const float4* __restrict__ x,
    const float4* __restrict__ wq, const float4* __restrict__ wk,
    const float4* __restrict__ wv, const float4* __restrict__ wo,
    const float4* __restrict__ bq, const float4* __restrict__ bk,
    const float4* __restrict__ bv,
    bf16x4* __restrict__ xb, bf16x4* __restrict__ wqkv,
    bf16x4* __restrict__ wob, float4* __restrict__ bcat)
{
  const int NX = NTOK * DMODEL / 4;       // 1048576 float4 groups of x
  const int NW = DMODEL * DMODEL / 4;     // 262144 per weight
  const int TOT = NX + 4 * NW + 3 * (DMODEL / 4);
  for (int g = blockIdx.x * 256 + threadIdx.x; g < TOT; g += gridDim.x * 256) {
    if (g < NX) {
      xb[g] = cvt4(x[g]);
    } else if (g < NX + 3 * NW) {
      int g2 = g - NX;
      const float4* s = (g2 < NW) ? wq : (g2 < 2 * NW ? wk : wv);
      wqkv[g2] = cvt4(s[g2 & (NW - 1)]);
    } else if (g < NX + 4 * NW) {
      int g3 = g - NX - 3 * NW;
      wob[g3] = cvt4(wo[g3]);
    } else {
      int g4 = g - NX - 4 * NW;
      const float4* s = (g4 < 256) ? bq : (g4 < 512 ? bk : bv);
      bcat[g4] = s[g4 & 255];
    }
  }
}

// ---------------- GEMM: C[M,N] = A[M,K] * W[N,K]^T + bias, K=1024 -------------
__global__ __launch_bounds__(256) void gemm128_bias(
    const __bf16* __restrict__ A, const __bf16* __restrict__ W,
    const float* __restrict__ bias, void* __restrict__ C,
    int ldc, int out_bf16)
{
  constexpr int K = 1024;
  __shared__ __bf16 sA[128 * 32];
  __shared__ __bf16 sB[128 * 32];
  const int tid  = threadIdx.x;
  const int wave = tid >> 6, lane = tid & 63;
  const int quad = lane >> 4, l16 = lane & 15;
  const size_t m0 = (size_t)blockIdx.x * 128;
  const size_t n0 = (size_t)blockIdx.y * 128;
  const int wm = (wave & 1) * 64, wn = (wave >> 1) * 64;

  const int g0 = wave * 2;
  const int sr = lane >> 2;          // row within 16-row group
  const int sc = (lane & 3) * 8;     // bf16 col offset within BK=32
  const __bf16* pa0 = A + (m0 + g0 * 16 + sr) * K + sc;
  const __bf16* pa1 = A + (m0 + g0 * 16 + 16 + sr) * K + sc;
  const __bf16* pb0 = W + (n0 + g0 * 16 + sr) * K + sc;
  const __bf16* pb1 = W + (n0 + g0 * 16 + 16 + sr) * K + sc;
  __bf16* la0 = sA + g0 * 512;
  __bf16* la1 = sA + g0 * 512 + 512;
  __bf16* lb0 = sB + g0 * 512;
  __bf16* lb1 = sB + g0 * 512 + 512;

  f32x4 acc[4][4];
  const f32x4 z = {0.f, 0.f, 0.f, 0.f};
#pragma unroll
  for (int i = 0; i < 4; ++i)
#pragma unroll
    for (int j = 0; j < 4; ++j) acc[i][j] = z;

  for (int k0 = 0; k0 < K; k0 += 32) {
    __syncthreads();                       // previous tile's reads done
    async_copy16(pa0 + k0, la0);
    async_copy16(pa1 + k0, la1);
    async_copy16(pb0 + k0, lb0);
    async_copy16(pb1 + k0, lb1);
    __syncthreads();                       // staging visible (vmcnt drained)

    bf16x8 af[4], bw[4];
#pragma unroll
    for (int i = 0; i < 4; ++i)
      af[i] = *(const bf16x8*)(sA + (wm + i * 16 + l16) * 32 + quad * 8);
#pragma unroll
    for (int j = 0; j < 4; ++j)
      bw[j] = *(const bf16x8*)(sB + (wn + j * 16 + l16) * 32 + quad * 8);
#pragma unroll
    for (int i = 0; i < 4; ++i)
#pragma unroll
      for (int j = 0; j < 4; ++j)
        acc[i][j] = MFMA_BF16(af[i], bw[j], acc[i][j]);
  }

  float bi[4];
#pragma unroll
  for (int j = 0; j < 4; ++j) bi[j] = bias[n0 + wn + j * 16 + l16];

#pragma unroll
  for (int i = 0; i < 4; ++i) {
#pragma unroll
    for (int j = 0; j < 4; ++j) {
#pragma unroll
      for (int r = 0; r < 4; ++r) {
        size_t row = m0 + wm + i * 16 + quad * 4 + r;
        size_t col = n0 + wn + j * 16 + l16;
        float v = acc[i][j][r] + bi[j];
        if (out_bf16) ((__bf16*)C)[row * ldc + col] = (__bf16)v;
        else          ((float*)C)[row * ldc + col] = v;
      }
    }
  }
}

// ---------------- V transpose: qkv v-slice (n, d) -> vt[(b,h,dk)][l] ----------
__global__ __launch_bounds__(256) void vtrans_kernel(
    const __bf16* __restrict__ qkv, __bf16* __restrict__ vt)
{
  __shared__ __bf16 t[64][66];
  const int tid = threadIdx.x;
  const int bh = blockIdx.x;           // b*16+h
  const int b = bh >> 4, h = bh & 15;
  const int l0 = blockIdx.y * 64;
  const int r4 = tid >> 6;             // 0..3
  const int c  = tid & 63;
#pragma unroll
  for (int rep = 0; rep < 16; ++rep) {
    int ll = rep * 4 + r4;
    t[ll][c] = qkv[(size_t)(b * SEQ + l0 + ll) * LDQKV + 2048 + h * DKH + c];
  }
  __syncthreads();
#pragma unroll
  for (int rep = 0; rep < 16; ++rep) {
    int dk = rep * 4 + r4;
    vt[(size_t)(bh * DKH + dk) * SEQ + l0 + c] = t[c][dk];
  }
}

// ---------------- MFMA flash attention (causal), split-K across 4 waves -------
// Block = 4 waves, ONE 16-query tile. Wave w processes key-tiles w, w+4, ...
// Fixed-shift softmax: p = exp2(s*0.125*log2e - 8*log2e)  -> partials additive:
// no running max, no alpha rescale, no per-tile shuffles. Merge = plain sums.
// NOTE: l_i is a PER-LANE partial (2 key-cols per lane) — must shuffle-reduce
// across the 16 lanes of each row group ONCE at loop end (Round-2 bug fix).
#define C2  0.18033688f     // 0.125 * log2(e)
#define CM  -11.5415603f    // -8 * log2(e)

__global__ __launch_bounds__(256) void attn_kernel(
    const __bf16* __restrict__ qkv,   // [4096][3072]
    const __bf16* __restrict__ vt,    // [32*64][2048]
    __bf16* __restrict__ attn)        // [4096][1024]
{
  __shared__ __bf16 pbuf[4][16 * 72]; // per-wave P buffer, row stride 72 bf16
  __shared__ float  obuf[4][64][20];  // per-wave O partials (+pad)
  __shared__ float  lbuf[4][16];      // per-wave l partials per query row
  const int tid  = threadIdx.x;
  const int wave = tid >> 6, lane = tid & 63;
  const int quad = lane >> 4, l16 = lane & 15;
  const int bh = blockIdx.y, b = bh >> 4, h = bh & 15;
  const int qt = 127 - blockIdx.x;            // longest q-tiles dispatch first
  const int q0 = qt * 16;
  const size_t tokbase = (size_t)b * SEQ;

  bf16x8 qf[2];
#pragma unroll
  for (int s = 0; s < 2; ++s)
    qf[s] = *(const bf16x8*)(qkv + (tokbase + q0 + l16) * LDQKV + h * DKH + s * 32 + quad * 8);

  f32x4 o[4];
  float l_i[4];
  const f32x4 z = {0.f, 0.f, 0.f, 0.f};
#pragma unroll
  for (int t = 0; t < 4; ++t) o[t] = z;
#pragma unroll
  for (int r = 0; r < 4; ++r) l_i[r] = 0.f;

  __bf16* pb = &pbuf[wave][0];
  const int ntiles = (q0 + 47) >> 5;

  const __bf16* kbase = qkv + (tokbase + l16) * LDQKV + 1024 + h * DKH + quad * 8;
  const __bf16* vbase = vt + ((size_t)bh * DKH + l16) * SEQ + quad * 8;

  for (int t0 = wave; t0 < ntiles; t0 += 4) {
    const int key0 = t0 * 32;

    bf16x8 kf[2][2], vf[4];
#pragma unroll
    for (int c = 0; c < 2; ++c)
#pragma unroll
      for (int s = 0; s < 2; ++s)
        kf[c][s] = *(const bf16x8*)(kbase + (size_t)(key0 + c * 16) * LDQKV + s * 32);
#pragma unroll
    for (int t = 0; t < 4; ++t)
      vf[t] = *(const bf16x8*)(vbase + (size_t)(t * 16) * SEQ + key0);

    f32x4 s0 = MFMA_BF16(qf[0], kf[0][0], z);
    s0 = MFMA_BF16(qf[1], kf[0][1], s0);
    f32x4 s1 = MFMA_BF16(qf[0], kf[1][0], z);
    s1 = MFMA_BF16(qf[1], kf[1][1], s1);

    float p0[4], p1[4];
    if (key0 + 31 <= q0) {
      // full tile: no causal mask needed
#pragma unroll
      for (int r = 0; r < 4; ++r) {
        p0[r] = exp2f(fmaf(s0[r], C2, CM));
        p1[r] = exp2f(fmaf(s1[r], C2, CM));
      }
    } else {
#pragma unroll
      for (int r = 0; r < 4; ++r) {
        const int gq = q0 + quad * 4 + r;
        float a = (key0 + l16      <= gq) ? s0[r] : -1e30f;
        float c = (key0 + 16 + l16 <= gq) ? s1[r] : -1e30f;
        p0[r] = exp2f(fmaf(a, C2, CM));
        p1[r] = exp2f(fmaf(c, C2, CM));
      }
    }

#pragma unroll
    for (int r = 0; r < 4; ++r) l_i[r] += p0[r] + p1[r];

    // P: C-layout -> per-wave LDS -> A-layout fragment
#pragma unroll
    for (int r = 0; r < 4; ++r) {
      const int row = quad * 4 + r;
      pb[row * 72 + l16]      = (__bf16)p0[r];
      pb[row * 72 + 16 + l16] = (__bf16)p1[r];
    }
    bf16x8 ap = *(const bf16x8*)(pb + l16 * 72 + quad * 8);

#pragma unroll
    for (int t = 0; t < 4; ++t) o[t] = MFMA_BF16(ap, vf[t], o[t]);
  }

  // reduce l_i across the 16 key-columns (lanes within row group) — BUG FIX
#pragma unroll
  for (int r = 0; r < 4; ++r) {
    float sm = l_i[r];
    sm += __shfl_xor(sm, 1);
    sm += __shfl_xor(sm, 2);
    sm += __shfl_xor(sm, 4);
    sm += __shfl_xor(sm, 8);
    l_i[r] = sm;
  }

  // ---- merge the 4 waves' partials (plain sums: fixed-shift softmax) ----
#pragma unroll
  for (int t = 0; t < 4; ++t)
    *(f32x4*)&obuf[wave][lane][t * 4] = o[t];
  if (l16 == 0) {
#pragma unroll
    for (int r = 0; r < 4; ++r) lbuf[wave][quad * 4 + r] = l_i[r];
  }
  __syncthreads();

  // wave w merges d-slice t=w and writes it
  f32x4 osum = z;
#pragma unroll
  for (int ww = 0; ww < 4; ++ww)
    osum += *(const f32x4*)&obuf[ww][lane][wave * 4];
  float linv[4];
#pragma unroll
  for (int r = 0; r < 4; ++r) {
    float ls = lbuf[0][quad * 4 + r] + lbuf[1][quad * 4 + r] +
               lbuf[2][quad * 4 + r] + lbuf[3][quad * 4 + r];
    linv[r] = 1.0f / ls;
  }
#pragma unroll
  for (int r = 0; r < 4; ++r)
    attn[(tokbase + q0 + quad * 4 + r) * DMODEL + h * DKH + wave * 16 + l16] =
        (__bf16)(osum[r] * linv[r]);
}

// ---------------- launch ------------------------------------------------------
extern "C" void kernel_launch(void* const* d_in, const int* in_sizes, int n_in,
                              void* d_out, int out_size, void* d_ws, size_t ws_size,
                              hipStream_t stream) {
  const float* x  = (const float*)d_in[0];
  const float* wq = (const float*)d_in[1];
  const float* bq = (const float*)d_in[2];
  const float* wk = (const float*)d_in[3];
  const float* bk = (const float*)d_in[4];
  const float* wv = (const float*)d_in[5];
  const float* bv = (const float*)d_in[6];
  const float* wo = (const float*)d_in[7];
  const float* bo = (const float*)d_in[8];

  char* ws = (char*)d_ws;
  __bf16* xb    = (__bf16*)(ws + 0);
  __bf16* wqkv  = (__bf16*)(ws + 8388608);
  __bf16* wob   = (__bf16*)(ws + 14680064);
  float*  bcat  = (float*)(ws + 16777216);
  __bf16* qkv   = (__bf16*)(ws + 16789504);
  __bf16* vt    = (__bf16*)(ws + 41955328);
  __bf16* attn  = (__bf16*)(ws + 50343936);
  float*  out   = (float*)d_out;

  pack_kernel<<<1024, 256, 0, stream>>>(
      (const float4*)x, (const float4*)wq, (const float4*)wk, (const float4*)wv,
      (const float4*)wo, (const float4*)bq, (const float4*)bk, (const float4*)bv,
      (bf16x4*)xb, (bf16x4*)wqkv, (bf16x4*)wob, (float4*)bcat);

  // fused QKV projection: M=4096, N=3072, K=1024
  gemm128_bias<<<dim3(32, 24), 256, 0, stream>>>(xb, wqkv, bcat, qkv, LDQKV, 1);

  vtrans_kernel<<<dim3(32, 32), 256, 0, stream>>>(qkv, vt);

  // flash attention: x = q-tile (reversed), y = bh
  attn_kernel<<<dim3(128, 32), 256, 0, stream>>>(qkv, vt, attn);

  // output projection: M=4096, N=1024, K=1024, fp32 out with bias bo
  gemm128_bias<<<dim3(32, 8), 256, 0, stream>>>(attn, wob, bo, out, DMODEL, 0);
}

// Round 4
// 220.927 us; speedup vs baseline: 1.4065x; 1.4065x over previous
//
#include <hip/hip_runtime.h>
#include <cstdint>

// Problem constants: B=2, L=2048, D=1024, H=16, DK=64
#define SEQ     2048
#define DMODEL  1024
#define NHEAD   16
#define DKH     64
#define NTOK    4096      // B*L
#define LDQKV   3072      // qkv buffer row stride (q|k|v)

typedef __bf16 bf16x8 __attribute__((ext_vector_type(8)));
typedef __bf16 bf16x4 __attribute__((ext_vector_type(4)));
typedef float  f32x4  __attribute__((ext_vector_type(4)));

#define MFMA_BF16(a, b, c) __builtin_amdgcn_mfma_f32_16x16x32_bf16((a), (b), (c), 0, 0, 0)

// async global->LDS copy, 16B per lane; LDS dest is wave-uniform base + lane*16
__device__ inline void async_copy16(const void* g, void* l) {
  __builtin_amdgcn_global_load_lds(
      reinterpret_cast<const __attribute__((address_space(1))) void*>(
          reinterpret_cast<uintptr_t>(g)),
      reinterpret_cast<__attribute__((address_space(3))) void*>(
          reinterpret_cast<uintptr_t>(l)),
      16, 0, 0);
}

__device__ inline bf16x4 cvt4(float4 v) {
  bf16x4 r;
  r[0] = (__bf16)v.x; r[1] = (__bf16)v.y; r[2] = (__bf16)v.z; r[3] = (__bf16)v.w;
  return r;
}

// ---------------- pack: fp32 -> bf16 casts + weight/bias concat ----------------
__global__ __launch_bounds__(256) void pack_kernel(
    const float4* __restrict__ x,
    const float4* __restrict__ wq, const float4* __restrict__ wk,
    const float4* __restrict__ wv, const float4* __restrict__ wo,
    const float4* __restrict__ bq, const float4* __restrict__ bk,
    const float4* __restrict__ bv,
    bf16x4* __restrict__ xb, bf16x4* __restrict__ wqkv,
    bf16x4* __restrict__ wob, float4* __restrict__ bcat)
{
  const int NX = NTOK * DMODEL / 4;       // 1048576 float4 groups of x
  const int NW = DMODEL * DMODEL / 4;     // 262144 per weight
  const int TOT = NX + 4 * NW + 3 * (DMODEL / 4);
  for (int g = blockIdx.x * 256 + threadIdx.x; g < TOT; g += gridDim.x * 256) {
    if (g < NX) {
      xb[g] = cvt4(x[g]);
    } else if (g < NX + 3 * NW) {
      int g2 = g - NX;
      const float4* s = (g2 < NW) ? wq : (g2 < 2 * NW ? wk : wv);
      wqkv[g2] = cvt4(s[g2 & (NW - 1)]);
    } else if (g < NX + 4 * NW) {
      int g3 = g - NX - 3 * NW;
      wob[g3] = cvt4(wo[g3]);
    } else {
      int g4 = g - NX - 4 * NW;
      const float4* s = (g4 < 256) ? bq : (g4 < 512 ? bk : bv);
      bcat[g4] = s[g4 & 255];
    }
  }
}

// ---------------- GEMM: C[M,N] = A[M,K] * W[N,K]^T + bias, K=1024 -------------
__global__ __launch_bounds__(256) void gemm128_bias(
    const __bf16* __restrict__ A, const __bf16* __restrict__ W,
    const float* __restrict__ bias, void* __restrict__ C,
    int ldc, int out_bf16)
{
  constexpr int K = 1024;
  __shared__ __bf16 sA[128 * 32];
  __shared__ __bf16 sB[128 * 32];
  const int tid  = threadIdx.x;
  const int wave = tid >> 6, lane = tid & 63;
  const int quad = lane >> 4, l16 = lane & 15;
  const size_t m0 = (size_t)blockIdx.x * 128;
  const size_t n0 = (size_t)blockIdx.y * 128;
  const int wm = (wave & 1) * 64, wn = (wave >> 1) * 64;

  const int g0 = wave * 2;
  const int sr = lane >> 2;          // row within 16-row group
  const int sc = (lane & 3) * 8;     // bf16 col offset within BK=32
  const __bf16* pa0 = A + (m0 + g0 * 16 + sr) * K + sc;
  const __bf16* pa1 = A + (m0 + g0 * 16 + 16 + sr) * K + sc;
  const __bf16* pb0 = W + (n0 + g0 * 16 + sr) * K + sc;
  const __bf16* pb1 = W + (n0 + g0 * 16 + 16 + sr) * K + sc;
  __bf16* la0 = sA + g0 * 512;
  __bf16* la1 = sA + g0 * 512 + 512;
  __bf16* lb0 = sB + g0 * 512;
  __bf16* lb1 = sB + g0 * 512 + 512;

  f32x4 acc[4][4];
  const f32x4 z = {0.f, 0.f, 0.f, 0.f};
#pragma unroll
  for (int i = 0; i < 4; ++i)
#pragma unroll
    for (int j = 0; j < 4; ++j) acc[i][j] = z;

  for (int k0 = 0; k0 < K; k0 += 32) {
    __syncthreads();                       // previous tile's reads done
    async_copy16(pa0 + k0, la0);
    async_copy16(pa1 + k0, la1);
    async_copy16(pb0 + k0, lb0);
    async_copy16(pb1 + k0, lb1);
    __syncthreads();                       // staging visible (vmcnt drained)

    bf16x8 af[4], bw[4];
#pragma unroll
    for (int i = 0; i < 4; ++i)
      af[i] = *(const bf16x8*)(sA + (wm + i * 16 + l16) * 32 + quad * 8);
#pragma unroll
    for (int j = 0; j < 4; ++j)
      bw[j] = *(const bf16x8*)(sB + (wn + j * 16 + l16) * 32 + quad * 8);
#pragma unroll
    for (int i = 0; i < 4; ++i)
#pragma unroll
      for (int j = 0; j < 4; ++j)
        acc[i][j] = MFMA_BF16(af[i], bw[j], acc[i][j]);
  }

  float bi[4];
#pragma unroll
  for (int j = 0; j < 4; ++j) bi[j] = bias[n0 + wn + j * 16 + l16];

#pragma unroll
  for (int i = 0; i < 4; ++i) {
#pragma unroll
    for (int j = 0; j < 4; ++j) {
#pragma unroll
      for (int r = 0; r < 4; ++r) {
        size_t row = m0 + wm + i * 16 + quad * 4 + r;
        size_t col = n0 + wn + j * 16 + l16;
        float v = acc[i][j][r] + bi[j];
        if (out_bf16) ((__bf16*)C)[row * ldc + col] = (__bf16)v;
        else          ((float*)C)[row * ldc + col] = v;
      }
    }
  }
}

// ---------------- V transpose: qkv v-slice (n, d) -> vt[(b,h,dk)][l] ----------
__global__ __launch_bounds__(256) void vtrans_kernel(
    const __bf16* __restrict__ qkv, __bf16* __restrict__ vt)
{
  __shared__ __bf16 t[64][66];
  const int tid = threadIdx.x;
  const int bh = blockIdx.x;           // b*16+h
  const int b = bh >> 4, h = bh & 15;
  const int l0 = blockIdx.y * 64;
  const int r4 = tid >> 6;             // 0..3
  const int c  = tid & 63;
#pragma unroll
  for (int rep = 0; rep < 16; ++rep) {
    int ll = rep * 4 + r4;
    t[ll][c] = qkv[(size_t)(b * SEQ + l0 + ll) * LDQKV + 2048 + h * DKH + c];
  }
  __syncthreads();
#pragma unroll
  for (int rep = 0; rep < 16; ++rep) {
    int dk = rep * 4 + r4;
    vt[(size_t)(bh * DKH + dk) * SEQ + l0 + c] = t[c][dk];
  }
}

// ---------------- MFMA flash attention (causal), GEMM-style block tiling ------
// Block = 4 waves x 16 queries = 64 queries. Per 64-key tile: K (64x64) and
// V^T (64x64) staged once into LDS (global_load_lds, XOR-swizzled 16B granules
// so staging stays contiguous AND b128 fragment reads are bank-balanced).
// Fixed-shift softmax (additive partials, no running max). No split-K.
// Grid swizzle: all 32 q-blocks of one bh share an XCD residue -> per-XCD K/V
// working set = 4 bh x 512 KB = 2 MB < 4 MB L2.
#define C2  0.18033688f     // 0.125 * log2(e)
#define CM  -11.5415603f    // -8 * log2(e)

__global__ __launch_bounds__(256) void attn_kernel(
    const __bf16* __restrict__ qkv,   // [4096][3072]
    const __bf16* __restrict__ vt,    // [32*64][2048]
    __bf16* __restrict__ attn)        // [4096][1024]
{
  __shared__ __bf16 sK[64 * 64];      // [key][dk], granule-swizzled
  __shared__ __bf16 sV[64 * 64];      // [dk][key], granule-swizzled
  __shared__ __bf16 pbuf[4][16 * 72]; // per-wave P buffer, row stride 72 bf16
  const int tid  = threadIdx.x;
  const int wave = tid >> 6, lane = tid & 63;
  const int quad = lane >> 4, l16 = lane & 15;
  const int id = blockIdx.x;
  const int bh = (id & 7) * 4 + (id >> 8);    // XCD-locality swizzle
  const int qb = 31 - ((id >> 3) & 31);       // longest q-blocks first
  const int b = bh >> 4, h = bh & 15;
  const int q0 = qb * 64;
  const int qw = q0 + wave * 16;              // wave's first query row
  const size_t tokbase = (size_t)b * SEQ;

  // staging source pointers: lane l -> (row = l>>3, swizzled granule (l&7)^(l>>3))
  const int srow = lane >> 3;
  const int sgr  = (lane & 7) ^ srow;
  const __bf16* pKsrc = qkv + (tokbase + wave * 16 + srow) * LDQKV + 1024 + h * DKH + sgr * 8;
  const __bf16* pVsrc = vt + ((size_t)bh * DKH + wave * 16 + srow) * SEQ + sgr * 8;
  __bf16* ldsK = sK + wave * 16 * 64;
  __bf16* ldsV = sV + wave * 16 * 64;

  bf16x8 qf[2];
#pragma unroll
  for (int s = 0; s < 2; ++s)
    qf[s] = *(const bf16x8*)(qkv + (tokbase + qw + l16) * LDQKV + h * DKH + s * 32 + quad * 8);

  f32x4 o[4];
  float l_i[4];
  const f32x4 z = {0.f, 0.f, 0.f, 0.f};
#pragma unroll
  for (int t = 0; t < 4; ++t) o[t] = z;
#pragma unroll
  for (int r = 0; r < 4; ++r) l_i[r] = 0.f;

  __bf16* pb = &pbuf[wave][0];
  const int swl = l16 & 7;   // read-side swizzle key

  for (int t0 = 0; t0 <= qb; ++t0) {
    const int key0 = t0 * 64;
    __syncthreads();                       // previous tile's reads done
    async_copy16(pKsrc + (size_t)key0 * LDQKV, ldsK);
    async_copy16(pKsrc + (size_t)(key0 + 8) * LDQKV, ldsK + 8 * 64);
    async_copy16(pVsrc + key0, ldsV);
    async_copy16(pVsrc + 8 * SEQ + key0, ldsV + 8 * 64);
    __syncthreads();                       // staging visible (vmcnt drained)

    // S = Q K^T : 4 col-tiles of 16 keys
    f32x4 sacc[4];
#pragma unroll
    for (int ct = 0; ct < 4; ++ct) {
      bf16x8 k0 = *(const bf16x8*)(sK + (ct * 16 + l16) * 64 + ((quad ^ swl) * 8));
      bf16x8 k1 = *(const bf16x8*)(sK + (ct * 16 + l16) * 64 + (((4 + quad) ^ swl) * 8));
      sacc[ct] = MFMA_BF16(qf[0], k0, z);
      sacc[ct] = MFMA_BF16(qf[1], k1, sacc[ct]);
    }

    float p[4][4];
    if (t0 < qb) {
      // full tile: always fully valid for every wave (key0+63 < qw)
#pragma unroll
      for (int ct = 0; ct < 4; ++ct)
#pragma unroll
        for (int r = 0; r < 4; ++r)
          p[ct][r] = exp2f(fmaf(sacc[ct][r], C2, CM));
    } else {
      // diagonal tile: key0 == q0; mask key > query
#pragma unroll
      for (int ct = 0; ct < 4; ++ct)
#pragma unroll
        for (int r = 0; r < 4; ++r) {
          float sv = (ct * 16 + l16 <= wave * 16 + quad * 4 + r) ? sacc[ct][r] : -1e30f;
          p[ct][r] = exp2f(fmaf(sv, C2, CM));
        }
    }
#pragma unroll
    for (int ct = 0; ct < 4; ++ct)
#pragma unroll
      for (int r = 0; r < 4; ++r) l_i[r] += p[ct][r];

    // P: C-layout -> per-wave LDS -> A-layout fragments (2 k-chunks)
#pragma unroll
    for (int r = 0; r < 4; ++r) {
      const int row = quad * 4 + r;
#pragma unroll
      for (int ct = 0; ct < 4; ++ct)
        pb[row * 72 + ct * 16 + l16] = (__bf16)p[ct][r];
    }
    bf16x8 ap0 = *(const bf16x8*)(pb + l16 * 72 + quad * 8);
    bf16x8 ap1 = *(const bf16x8*)(pb + l16 * 72 + 32 + quad * 8);

    // O += P V : 4 dk-tiles
#pragma unroll
    for (int dt = 0; dt < 4; ++dt) {
      bf16x8 v0 = *(const bf16x8*)(sV + (dt * 16 + l16) * 64 + ((quad ^ swl) * 8));
      bf16x8 v1 = *(const bf16x8*)(sV + (dt * 16 + l16) * 64 + (((4 + quad) ^ swl) * 8));
      o[dt] = MFMA_BF16(ap0, v0, o[dt]);
      o[dt] = MFMA_BF16(ap1, v1, o[dt]);
    }
  }

  // l_i is per-lane (4 key-cols); reduce across the 16 lanes of the row group
  float linv[4];
#pragma unroll
  for (int r = 0; r < 4; ++r) {
    float sm = l_i[r];
    sm += __shfl_xor(sm, 1);
    sm += __shfl_xor(sm, 2);
    sm += __shfl_xor(sm, 4);
    sm += __shfl_xor(sm, 8);
    linv[r] = 1.0f / sm;
  }

#pragma unroll
  for (int dt = 0; dt < 4; ++dt)
#pragma unroll
    for (int r = 0; r < 4; ++r)
      attn[(tokbase + qw + quad * 4 + r) * DMODEL + h * DKH + dt * 16 + l16] =
          (__bf16)(o[dt][r] * linv[r]);
}

// ---------------- launch ------------------------------------------------------
extern "C" void kernel_launch(void* const* d_in, const int* in_sizes, int n_in,
                              void* d_out, int out_size, void* d_ws, size_t ws_size,
                              hipStream_t stream) {
  const float* x  = (const float*)d_in[0];
  const float* wq = (const float*)d_in[1];
  const float* bq = (const float*)d_in[2];
  const float* wk = (const float*)d_in[3];
  const float* bk = (const float*)d_in[4];
  const float* wv = (const float*)d_in[5];
  const float* bv = (const float*)d_in[6];
  const float* wo = (const float*)d_in[7];
  const float* bo = (const float*)d_in[8];

  char* ws = (char*)d_ws;
  __bf16* xb    = (__bf16*)(ws + 0);
  __bf16* wqkv  = (__bf16*)(ws + 8388608);
  __bf16* wob   = (__bf16*)(ws + 14680064);
  float*  bcat  = (float*)(ws + 16777216);
  __bf16* qkv   = (__bf16*)(ws + 16789504);
  __bf16* vt    = (__bf16*)(ws + 41955328);
  __bf16* attn  = (__bf16*)(ws + 50343936);
  float*  out   = (float*)d_out;

  pack_kernel<<<1024, 256, 0, stream>>>(
      (const float4*)x, (const float4*)wq, (const float4*)wk, (const float4*)wv,
      (const float4*)wo, (const float4*)bq, (const float4*)bk, (const float4*)bv,
      (bf16x4*)xb, (bf16x4*)wqkv, (bf16x4*)wob, (float4*)bcat);

  // fused QKV projection: M=4096, N=3072, K=1024
  gemm128_bias<<<dim3(32, 24), 256, 0, stream>>>(xb, wqkv, bcat, qkv, LDQKV, 1);

  vtrans_kernel<<<dim3(32, 32), 256, 0, stream>>>(qkv, vt);

  // flash attention: 1-D grid, swizzled (bh, qb)
  attn_kernel<<<1024, 256, 0, stream>>>(qkv, vt, attn);

  // output projection: M=4096, N=1024, K=1024, fp32 out with bias bo
  gemm128_bias<<<dim3(32, 8), 256, 0, stream>>>(attn, wob, bo, out, DMODEL, 0);
}

// Round 5
// 191.058 us; speedup vs baseline: 1.6264x; 1.1563x over previous
//
#include <hip/hip_runtime.h>
#include <cstdint>

// Problem constants: B=2, L=2048, D=1024, H=16, DK=64
#define SEQ     2048
#define DMODEL  1024
#define NHEAD   16
#define DKH     64
#define NTOK    4096      // B*L
#define LDQKV   3072      // qkv buffer row stride (q|k|v)

typedef __bf16 bf16x8 __attribute__((ext_vector_type(8)));
typedef __bf16 bf16x4 __attribute__((ext_vector_type(4)));
typedef float  f32x4  __attribute__((ext_vector_type(4)));

#define MFMA_BF16(a, b, c) __builtin_amdgcn_mfma_f32_16x16x32_bf16((a), (b), (c), 0, 0, 0)

// async global->LDS copy, 16B per lane; LDS dest is wave-uniform base + lane*16
__device__ inline void async_copy16(const void* g, void* l) {
  __builtin_amdgcn_global_load_lds(
      reinterpret_cast<const __attribute__((address_space(1))) void*>(
          reinterpret_cast<uintptr_t>(g)),
      reinterpret_cast<__attribute__((address_space(3))) void*>(
          reinterpret_cast<uintptr_t>(l)),
      16, 0, 0);
}

__device__ inline bf16x4 cvt4(float4 v) {
  bf16x4 r;
  r[0] = (__bf16)v.x; r[1] = (__bf16)v.y; r[2] = (__bf16)v.z; r[3] = (__bf16)v.w;
  return r;
}

// ---------------- pack: fp32 -> bf16 casts + weight/bias concat ----------------
__global__ __launch_bounds__(256) void pack_kernel(
    const float4* __restrict__ x,
    const float4* __restrict__ wq, const float4* __restrict__ wk,
    const float4* __restrict__ wv, const float4* __restrict__ wo,
    const float4* __restrict__ bq, const float4* __restrict__ bk,
    const float4* __restrict__ bv,
    bf16x4* __restrict__ xb, bf16x4* __restrict__ wqkv,
    bf16x4* __restrict__ wob, float4* __restrict__ bcat)
{
  const int NX = NTOK * DMODEL / 4;       // 1048576 float4 groups of x
  const int NW = DMODEL * DMODEL / 4;     // 262144 per weight
  const int TOT = NX + 4 * NW + 3 * (DMODEL / 4);
  for (int g = blockIdx.x * 256 + threadIdx.x; g < TOT; g += gridDim.x * 256) {
    if (g < NX) {
      xb[g] = cvt4(x[g]);
    } else if (g < NX + 3 * NW) {
      int g2 = g - NX;
      const float4* s = (g2 < NW) ? wq : (g2 < 2 * NW ? wk : wv);
      wqkv[g2] = cvt4(s[g2 & (NW - 1)]);
    } else if (g < NX + 4 * NW) {
      int g3 = g - NX - 3 * NW;
      wob[g3] = cvt4(wo[g3]);
    } else {
      int g4 = g - NX - 4 * NW;
      const float4* s = (g4 < 256) ? bq : (g4 < 512 ? bk : bv);
      bcat[g4] = s[g4 & 255];
    }
  }
}

// ---------------- GEMM: C[M,N] = A[M,K] * W[N,K]^T + bias, K=1024 -------------
// 128x128 tile, double-buffered LDS staging (one barrier per K-step; tile k+1
// loads stay in flight across compute of tile k — helps the 1-wave/SIMD
// out-projection where staging latency is fully exposed).
__global__ __launch_bounds__(256) void gemm128_bias(
    const __bf16* __restrict__ A, const __bf16* __restrict__ W,
    const float* __restrict__ bias, void* __restrict__ C,
    int ldc, int out_bf16)
{
  constexpr int K = 1024;
  __shared__ __bf16 sA[2][128 * 32];
  __shared__ __bf16 sB[2][128 * 32];
  const int tid  = threadIdx.x;
  const int wave = tid >> 6, lane = tid & 63;
  const int quad = lane >> 4, l16 = lane & 15;
  const size_t m0 = (size_t)blockIdx.x * 128;
  const size_t n0 = (size_t)blockIdx.y * 128;
  const int wm = (wave & 1) * 64, wn = (wave >> 1) * 64;

  const int g0 = wave * 2;
  const int sr = lane >> 2;          // row within 16-row group
  const int sc = (lane & 3) * 8;     // bf16 col offset within BK=32
  const __bf16* pa0 = A + (m0 + g0 * 16 + sr) * K + sc;
  const __bf16* pa1 = pa0 + 16 * K;
  const __bf16* pb0 = W + (n0 + g0 * 16 + sr) * K + sc;
  const __bf16* pb1 = pb0 + 16 * K;
  const int lo = g0 * 512;

  f32x4 acc[4][4];
  const f32x4 z = {0.f, 0.f, 0.f, 0.f};
#pragma unroll
  for (int i = 0; i < 4; ++i)
#pragma unroll
    for (int j = 0; j < 4; ++j) acc[i][j] = z;

  // prologue: stage k0=0 into buffer 0
  async_copy16(pa0, &sA[0][lo]);
  async_copy16(pa1, &sA[0][lo + 512]);
  async_copy16(pb0, &sB[0][lo]);
  async_copy16(pb1, &sB[0][lo + 512]);

  for (int k0 = 0; k0 < K; k0 += 32) {
    const int cur = (k0 >> 5) & 1, nxt = cur ^ 1;
    __syncthreads();                 // tile k0 staged; prev reads of nxt done
    if (k0 + 32 < K) {
      async_copy16(pa0 + k0 + 32, &sA[nxt][lo]);
      async_copy16(pa1 + k0 + 32, &sA[nxt][lo + 512]);
      async_copy16(pb0 + k0 + 32, &sB[nxt][lo]);
      async_copy16(pb1 + k0 + 32, &sB[nxt][lo + 512]);
    }

    bf16x8 af[4], bw[4];
#pragma unroll
    for (int i = 0; i < 4; ++i)
      af[i] = *(const bf16x8*)(&sA[cur][(wm + i * 16 + l16) * 32 + quad * 8]);
#pragma unroll
    for (int j = 0; j < 4; ++j)
      bw[j] = *(const bf16x8*)(&sB[cur][(wn + j * 16 + l16) * 32 + quad * 8]);
#pragma unroll
    for (int i = 0; i < 4; ++i)
#pragma unroll
      for (int j = 0; j < 4; ++j)
        acc[i][j] = MFMA_BF16(af[i], bw[j], acc[i][j]);
  }

  float bi[4];
#pragma unroll
  for (int j = 0; j < 4; ++j) bi[j] = bias[n0 + wn + j * 16 + l16];

#pragma unroll
  for (int i = 0; i < 4; ++i) {
#pragma unroll
    for (int j = 0; j < 4; ++j) {
#pragma unroll
      for (int r = 0; r < 4; ++r) {
        size_t row = m0 + wm + i * 16 + quad * 4 + r;
        size_t col = n0 + wn + j * 16 + l16;
        float v = acc[i][j][r] + bi[j];
        if (out_bf16) ((__bf16*)C)[row * ldc + col] = (__bf16)v;
        else          ((float*)C)[row * ldc + col] = v;
      }
    }
  }
}

// ---------------- V transpose: qkv v-slice (n, d) -> vt[(b,h,dk)][l] ----------
__global__ __launch_bounds__(256) void vtrans_kernel(
    const __bf16* __restrict__ qkv, __bf16* __restrict__ vt)
{
  __shared__ __bf16 t[64][66];
  const int tid = threadIdx.x;
  const int bh = blockIdx.x;           // b*16+h
  const int b = bh >> 4, h = bh & 15;
  const int l0 = blockIdx.y * 64;
  const int r4 = tid >> 6;             // 0..3
  const int c  = tid & 63;
#pragma unroll
  for (int rep = 0; rep < 16; ++rep) {
    int ll = rep * 4 + r4;
    t[ll][c] = qkv[(size_t)(b * SEQ + l0 + ll) * LDQKV + 2048 + h * DKH + c];
  }
  __syncthreads();
#pragma unroll
  for (int rep = 0; rep < 16; ++rep) {
    int dk = rep * 4 + r4;
    vt[(size_t)(bh * DKH + dk) * SEQ + l0 + c] = t[c][dk];
  }
}

// ---------------- MFMA flash attention (causal) -------------------------------
// Block = 4 waves x 16 queries = 64 queries; K/V^T 64x64 tiles double-buffered
// in LDS. Fixed-shift softmax (additive partials). Balanced schedule:
// u=(id>>3)&31, v=id&7, w=id>>8; bh=v*4+w (XCD locality: one XCD sees 4 bh);
// qb=(w&1)?u:31-u  ->  each CU's 4 round-robin blocks sum to exactly 66
// key-tile iterations (fixes the round-4 qb-aliased imbalance).
#define C2  0.18033688f     // 0.125 * log2(e)
#define CM  -11.5415603f    // -8 * log2(e)

__global__ __launch_bounds__(256) void attn_kernel(
    const __bf16* __restrict__ qkv,   // [4096][3072]
    const __bf16* __restrict__ vt,    // [32*64][2048]
    __bf16* __restrict__ attn)        // [4096][1024]
{
  __shared__ __bf16 sK[2][64 * 64];   // [key][dk], granule-swizzled
  __shared__ __bf16 sV[2][64 * 64];   // [dk][key], granule-swizzled
  __shared__ __bf16 pbuf[4][16 * 64]; // per-wave P buffer, granule-swizzled
  const int tid  = threadIdx.x;
  const int wave = tid >> 6, lane = tid & 63;
  const int quad = lane >> 4, l16 = lane & 15;
  const int id = blockIdx.x;
  const int u = (id >> 3) & 31, v = id & 7, w = id >> 8;
  const int bh = v * 4 + w;
  const int qb = (w & 1) ? u : 31 - u;
  const int b = bh >> 4, h = bh & 15;
  const int q0 = qb * 64;
  const int qw = q0 + wave * 16;              // wave's first query row
  const size_t tokbase = (size_t)b * SEQ;

  // staging: lane l -> (row = l>>3, swizzled granule (l&7)^(l>>3))
  const int srow = lane >> 3;
  const int sgr  = (lane & 7) ^ srow;
  const __bf16* pKsrc = qkv + (tokbase + wave * 16 + srow) * LDQKV + 1024 + h * DKH + sgr * 8;
  const __bf16* pVsrc = vt + ((size_t)bh * DKH + wave * 16 + srow) * SEQ + sgr * 8;
  const int lo = wave * 16 * 64;              // wave's slab within buffer

  bf16x8 qf[2];
#pragma unroll
  for (int s = 0; s < 2; ++s)
    qf[s] = *(const bf16x8*)(qkv + (tokbase + qw + l16) * LDQKV + h * DKH + s * 32 + quad * 8);

  f32x4 o[4];
  float l_i[4];
  const f32x4 z = {0.f, 0.f, 0.f, 0.f};
#pragma unroll
  for (int t = 0; t < 4; ++t) o[t] = z;
#pragma unroll
  for (int r = 0; r < 4; ++r) l_i[r] = 0.f;

  __bf16* pb = &pbuf[wave][0];
  const int swl = l16 & 7;   // read-side swizzle key

  // prologue: stage key-tile 0 into buffer 0
  async_copy16(pKsrc, &sK[0][lo]);
  async_copy16(pKsrc + (size_t)8 * LDQKV, &sK[0][lo + 8 * 64]);
  async_copy16(pVsrc, &sV[0][lo]);
  async_copy16(pVsrc + (size_t)8 * SEQ, &sV[0][lo + 8 * 64]);

  for (int t0 = 0; t0 <= qb; ++t0) {
    const int cur = t0 & 1, nxt = cur ^ 1;
    __syncthreads();                 // tile t0 staged; prev reads of nxt done
    if (t0 < qb) {
      const size_t koff = (size_t)(t0 + 1) * 64;
      async_copy16(pKsrc + koff * LDQKV, &sK[nxt][lo]);
      async_copy16(pKsrc + (koff + 8) * LDQKV, &sK[nxt][lo + 8 * 64]);
      async_copy16(pVsrc + koff, &sV[nxt][lo]);
      async_copy16(pVsrc + (size_t)8 * SEQ + koff, &sV[nxt][lo + 8 * 64]);
    }
    const __bf16* K_ = &sK[cur][0];
    const __bf16* V_ = &sV[cur][0];

    // S = Q K^T : 4 col-tiles of 16 keys
    f32x4 sacc[4];
#pragma unroll
    for (int ct = 0; ct < 4; ++ct) {
      bf16x8 k0 = *(const bf16x8*)(K_ + (ct * 16 + l16) * 64 + ((quad ^ swl) * 8));
      bf16x8 k1 = *(const bf16x8*)(K_ + (ct * 16 + l16) * 64 + (((4 + quad) ^ swl) * 8));
      sacc[ct] = MFMA_BF16(qf[0], k0, z);
      sacc[ct] = MFMA_BF16(qf[1], k1, sacc[ct]);
    }

    float p[4][4];
    if (t0 < qb) {
      // full tile: fully valid for every wave (key0+63 < qw)
#pragma unroll
      for (int ct = 0; ct < 4; ++ct)
#pragma unroll
        for (int r = 0; r < 4; ++r)
          p[ct][r] = exp2f(fmaf(sacc[ct][r], C2, CM));
    } else {
      // diagonal tile: key0 == q0; mask key > query
#pragma unroll
      for (int ct = 0; ct < 4; ++ct)
#pragma unroll
        for (int r = 0; r < 4; ++r) {
          float sv = (ct * 16 + l16 <= wave * 16 + quad * 4 + r) ? sacc[ct][r] : -1e30f;
          p[ct][r] = exp2f(fmaf(sv, C2, CM));
        }
    }
#pragma unroll
    for (int ct = 0; ct < 4; ++ct)
#pragma unroll
      for (int r = 0; r < 4; ++r) l_i[r] += p[ct][r];

    // P: C-layout -> per-wave LDS (granule-swizzled) -> A-layout fragments
#pragma unroll
    for (int r = 0; r < 4; ++r) {
      const int row = quad * 4 + r;
      const int rsw = row & 7;
#pragma unroll
      for (int ct = 0; ct < 4; ++ct) {
        const int gk = ct * 2 + (l16 >> 3);
        pb[row * 64 + ((gk ^ rsw) * 8) + (l16 & 7)] = (__bf16)p[ct][r];
      }
    }
    bf16x8 ap0 = *(const bf16x8*)(pb + l16 * 64 + ((quad ^ swl) * 8));
    bf16x8 ap1 = *(const bf16x8*)(pb + l16 * 64 + (((4 + quad) ^ swl) * 8));

    // O += P V : 4 dk-tiles
#pragma unroll
    for (int dt = 0; dt < 4; ++dt) {
      bf16x8 v0 = *(const bf16x8*)(V_ + (dt * 16 + l16) * 64 + ((quad ^ swl) * 8));
      bf16x8 v1 = *(const bf16x8*)(V_ + (dt * 16 + l16) * 64 + (((4 + quad) ^ swl) * 8));
      o[dt] = MFMA_BF16(ap0, v0, o[dt]);
      o[dt] = MFMA_BF16(ap1, v1, o[dt]);
    }
  }

  // l_i is per-lane (4 key-cols); reduce across the 16 lanes of the row group
  float linv[4];
#pragma unroll
  for (int r = 0; r < 4; ++r) {
    float sm = l_i[r];
    sm += __shfl_xor(sm, 1);
    sm += __shfl_xor(sm, 2);
    sm += __shfl_xor(sm, 4);
    sm += __shfl_xor(sm, 8);
    linv[r] = 1.0f / sm;
  }

#pragma unroll
  for (int dt = 0; dt < 4; ++dt)
#pragma unroll
    for (int r = 0; r < 4; ++r)
      attn[(tokbase + qw + quad * 4 + r) * DMODEL + h * DKH + dt * 16 + l16] =
          (__bf16)(o[dt][r] * linv[r]);
}

// ---------------- launch ------------------------------------------------------
extern "C" void kernel_launch(void* const* d_in, const int* in_sizes, int n_in,
                              void* d_out, int out_size, void* d_ws, size_t ws_size,
                              hipStream_t stream) {
  const float* x  = (const float*)d_in[0];
  const float* wq = (const float*)d_in[1];
  const float* bq = (const float*)d_in[2];
  const float* wk = (const float*)d_in[3];
  const float* bk = (const float*)d_in[4];
  const float* wv = (const float*)d_in[5];
  const float* bv = (const float*)d_in[6];
  const float* wo = (const float*)d_in[7];
  const float* bo = (const float*)d_in[8];

  char* ws = (char*)d_ws;
  __bf16* xb    = (__bf16*)(ws + 0);
  __bf16* wqkv  = (__bf16*)(ws + 8388608);
  __bf16* wob   = (__bf16*)(ws + 14680064);
  float*  bcat  = (float*)(ws + 16777216);
  __bf16* qkv   = (__bf16*)(ws + 16789504);
  __bf16* vt    = (__bf16*)(ws + 41955328);
  __bf16* attn  = (__bf16*)(ws + 50343936);
  float*  out   = (float*)d_out;

  pack_kernel<<<1024, 256, 0, stream>>>(
      (const float4*)x, (const float4*)wq, (const float4*)wk, (const float4*)wv,
      (const float4*)wo, (const float4*)bq, (const float4*)bk, (const float4*)bv,
      (bf16x4*)xb, (bf16x4*)wqkv, (bf16x4*)wob, (float4*)bcat);

  // fused QKV projection: M=4096, N=3072, K=1024
  gemm128_bias<<<dim3(32, 24), 256, 0, stream>>>(xb, wqkv, bcat, qkv, LDQKV, 1);

  vtrans_kernel<<<dim3(32, 32), 256, 0, stream>>>(qkv, vt);

  // flash attention: 1-D grid, balanced swizzle
  attn_kernel<<<1024, 256, 0, stream>>>(qkv, vt, attn);

  // output projection: M=4096, N=1024, K=1024, fp32 out with bias bo
  gemm128_bias<<<dim3(32, 8), 256, 0, stream>>>(attn, wob, bo, out, DMODEL, 0);
}

// Round 6
// 182.183 us; speedup vs baseline: 1.7056x; 1.0487x over previous
//
#include <hip/hip_runtime.h>
#include <cstdint>

// Problem constants: B=2, L=2048, D=1024, H=16, DK=64
#define SEQ     2048
#define DMODEL  1024
#define NHEAD   16
#define DKH     64
#define NTOK    4096      // B*L
#define LDQKV   3072      // qkv buffer row stride (q|k|v)

typedef __bf16 bf16x8 __attribute__((ext_vector_type(8)));
typedef __bf16 bf16x4 __attribute__((ext_vector_type(4)));
typedef float  f32x4  __attribute__((ext_vector_type(4)));

#define MFMA_BF16(a, b, c) __builtin_amdgcn_mfma_f32_16x16x32_bf16((a), (b), (c), 0, 0, 0)

// 0.125 * log2(e): folded into wq/bq at pack time. Softmax shift dropped
// entirely — exp2(s) scales O and l identically, cancels in O/l.
#define C2F 0.18033688f

// async global->LDS copy, 16B per lane; LDS dest is wave-uniform base + lane*16
__device__ inline void async_copy16(const void* g, void* l) {
  __builtin_amdgcn_global_load_lds(
      reinterpret_cast<const __attribute__((address_space(1))) void*>(
          reinterpret_cast<uintptr_t>(g)),
      reinterpret_cast<__attribute__((address_space(3))) void*>(
          reinterpret_cast<uintptr_t>(l)),
      16, 0, 0);
}

__device__ inline bf16x4 cvt4(float4 v) {
  bf16x4 r;
  r[0] = (__bf16)v.x; r[1] = (__bf16)v.y; r[2] = (__bf16)v.z; r[3] = (__bf16)v.w;
  return r;
}

// ---------------- pack: fp32 -> bf16 casts + weight/bias concat ----------------
// wq and bq are pre-scaled by C2F (softmax scale folded into Q).
__global__ __launch_bounds__(256) void pack_kernel(
    const float4* __restrict__ x,
    const float4* __restrict__ wq, const float4* __restrict__ wk,
    const float4* __restrict__ wv, const float4* __restrict__ wo,
    const float4* __restrict__ bq, const float4* __restrict__ bk,
    const float4* __restrict__ bv,
    bf16x4* __restrict__ xb, bf16x4* __restrict__ wqkv,
    bf16x4* __restrict__ wob, float4* __restrict__ bcat)
{
  const int NX = NTOK * DMODEL / 4;       // 1048576 float4 groups of x
  const int NW = DMODEL * DMODEL / 4;     // 262144 per weight
  const int TOT = NX + 4 * NW + 3 * (DMODEL / 4);
  for (int g = blockIdx.x * 256 + threadIdx.x; g < TOT; g += gridDim.x * 256) {
    if (g < NX) {
      xb[g] = cvt4(x[g]);
    } else if (g < NX + 3 * NW) {
      int g2 = g - NX;
      const float4* s = (g2 < NW) ? wq : (g2 < 2 * NW ? wk : wv);
      float4 v = s[g2 & (NW - 1)];
      if (g2 < NW) { v.x *= C2F; v.y *= C2F; v.z *= C2F; v.w *= C2F; }
      wqkv[g2] = cvt4(v);
    } else if (g < NX + 4 * NW) {
      int g3 = g - NX - 3 * NW;
      wob[g3] = cvt4(wo[g3]);
    } else {
      int g4 = g - NX - 4 * NW;
      const float4* s = (g4 < 256) ? bq : (g4 < 512 ? bk : bv);
      float4 v = s[g4 & 255];
      if (g4 < 256) { v.x *= C2F; v.y *= C2F; v.z *= C2F; v.w *= C2F; }
      bcat[g4] = v;
    }
  }
}

// ---------------- GEMM: C[M,N] = A[M,K] * W[N,K]^T + bias, K=1024 -------------
// 128xBN tile (BN=128 or 64), double-buffered LDS staging.
template<int BN>
__global__ __launch_bounds__(256) void gemm_bias(
    const __bf16* __restrict__ A, const __bf16* __restrict__ W,
    const float* __restrict__ bias, void* __restrict__ C,
    int ldc, int out_bf16)
{
  constexpr int K = 1024;
  constexpr int JT = BN / 32;          // j-tiles per wave: 4 or 2
  __shared__ __bf16 sA[2][128 * 32];
  __shared__ __bf16 sB[2][BN * 32];
  const int tid  = threadIdx.x;
  const int wave = tid >> 6, lane = tid & 63;
  const int quad = lane >> 4, l16 = lane & 15;
  const size_t m0 = (size_t)blockIdx.x * 128;
  const size_t n0 = (size_t)blockIdx.y * BN;
  const int wm = (wave & 1) * 64, wn = (wave >> 1) * (BN / 2);

  const int g0 = wave * 2;
  const int sr = lane >> 2;          // row within 16-row group
  const int sc = (lane & 3) * 8;     // bf16 col offset within BK=32
  const __bf16* pa0 = A + (m0 + g0 * 16 + sr) * K + sc;
  const __bf16* pa1 = pa0 + 16 * K;
  const int brow = (BN == 128) ? g0 * 16 : wave * 16;
  const __bf16* pb0 = W + (n0 + brow + sr) * K + sc;
  const int lo  = g0 * 512;
  const int lob = (BN == 128) ? g0 * 512 : wave * 512;

  f32x4 acc[4][JT];
  const f32x4 z = {0.f, 0.f, 0.f, 0.f};
#pragma unroll
  for (int i = 0; i < 4; ++i)
#pragma unroll
    for (int j = 0; j < JT; ++j) acc[i][j] = z;

  // prologue: stage k0=0 into buffer 0
  async_copy16(pa0, &sA[0][lo]);
  async_copy16(pa1, &sA[0][lo + 512]);
  async_copy16(pb0, &sB[0][lob]);
  if (BN == 128) async_copy16(pb0 + 16 * K, &sB[0][lob + 512]);

  for (int k0 = 0; k0 < K; k0 += 32) {
    const int cur = (k0 >> 5) & 1, nxt = cur ^ 1;
    __syncthreads();                 // tile k0 staged; prev reads of nxt done
    if (k0 + 32 < K) {
      async_copy16(pa0 + k0 + 32, &sA[nxt][lo]);
      async_copy16(pa1 + k0 + 32, &sA[nxt][lo + 512]);
      async_copy16(pb0 + k0 + 32, &sB[nxt][lob]);
      if (BN == 128) async_copy16(pb0 + 16 * K + k0 + 32, &sB[nxt][lob + 512]);
    }

    bf16x8 af[4], bw[JT];
#pragma unroll
    for (int i = 0; i < 4; ++i)
      af[i] = *(const bf16x8*)(&sA[cur][(wm + i * 16 + l16) * 32 + quad * 8]);
#pragma unroll
    for (int j = 0; j < JT; ++j)
      bw[j] = *(const bf16x8*)(&sB[cur][(wn + j * 16 + l16) * 32 + quad * 8]);
#pragma unroll
    for (int i = 0; i < 4; ++i)
#pragma unroll
      for (int j = 0; j < JT; ++j)
        acc[i][j] = MFMA_BF16(af[i], bw[j], acc[i][j]);
  }

  float bi[JT];
#pragma unroll
  for (int j = 0; j < JT; ++j) bi[j] = bias[n0 + wn + j * 16 + l16];

#pragma unroll
  for (int i = 0; i < 4; ++i) {
#pragma unroll
    for (int j = 0; j < JT; ++j) {
#pragma unroll
      for (int r = 0; r < 4; ++r) {
        size_t row = m0 + wm + i * 16 + quad * 4 + r;
        size_t col = n0 + wn + j * 16 + l16;
        float v = acc[i][j][r] + bi[j];
        if (out_bf16) ((__bf16*)C)[row * ldc + col] = (__bf16)v;
        else          ((float*)C)[row * ldc + col] = v;
      }
    }
  }
}

// ---------------- V transpose: qkv v-slice (n, d) -> vt[(b,h,dk)][l] ----------
__global__ __launch_bounds__(256) void vtrans_kernel(
    const __bf16* __restrict__ qkv, __bf16* __restrict__ vt)
{
  __shared__ __bf16 t[64][66];
  const int tid = threadIdx.x;
  const int bh = blockIdx.x;           // b*16+h
  const int b = bh >> 4, h = bh & 15;
  const int l0 = blockIdx.y * 64;
  const int r4 = tid >> 6;             // 0..3
  const int c  = tid & 63;
#pragma unroll
  for (int rep = 0; rep < 16; ++rep) {
    int ll = rep * 4 + r4;
    t[ll][c] = qkv[(size_t)(b * SEQ + l0 + ll) * LDQKV + 2048 + h * DKH + c];
  }
  __syncthreads();
#pragma unroll
  for (int rep = 0; rep < 16; ++rep) {
    int dk = rep * 4 + r4;
    vt[(size_t)(bh * DKH + dk) * SEQ + l0 + c] = t[c][dk];
  }
}

// ---------------- MFMA flash attention (causal) -------------------------------
// Block = 4 waves x 16 queries; K/V^T 64x64 tiles double-buffered in LDS.
// S^T trick: compute K Q^T (swapped operands) so each lane holds 4 CONSECUTIVE
// keys for ONE query -> P repack is 4 packed ds_write_b64 (vs 16 b16 stores).
// No scale/shift in softmax (folded into wq; shift cancels in O/l).
// Row-sums l via MFMA with ones-B: lands in C-layout rows, zero shuffles.
// Balanced schedule as round 5 (each CU's 4 blocks sum to 66 iterations).
__global__ __launch_bounds__(256) void attn_kernel(
    const __bf16* __restrict__ qkv,   // [4096][3072]
    const __bf16* __restrict__ vt,    // [32*64][2048]
    __bf16* __restrict__ attn)        // [4096][1024]
{
  __shared__ __bf16 sK[2][64 * 64];   // [key][dk], granule-swizzled
  __shared__ __bf16 sV[2][64 * 64];   // [dk][key], granule-swizzled
  __shared__ __bf16 pbuf[4][16 * 64]; // per-wave P, [q][k] XOR-granule swizzle
  const int tid  = threadIdx.x;
  const int wave = tid >> 6, lane = tid & 63;
  const int quad = lane >> 4, l16 = lane & 15;
  const int id = blockIdx.x;
  const int u = (id >> 3) & 31, v = id & 7, w = id >> 8;
  const int bh = v * 4 + w;
  const int qb = (w & 1) ? u : 31 - u;
  const int b = bh >> 4, h = bh & 15;
  const int q0 = qb * 64;
  const int qw = q0 + wave * 16;              // wave's first query row
  const size_t tokbase = (size_t)b * SEQ;

  // staging: lane l -> (row = l>>3, swizzled granule (l&7)^(l>>3))
  const int srow = lane >> 3;
  const int sgr  = (lane & 7) ^ srow;
  const __bf16* pKsrc = qkv + (tokbase + wave * 16 + srow) * LDQKV + 1024 + h * DKH + sgr * 8;
  const __bf16* pVsrc = vt + ((size_t)bh * DKH + wave * 16 + srow) * SEQ + sgr * 8;
  const int lo = wave * 16 * 64;              // wave's slab within buffer

  bf16x8 qf[2];
#pragma unroll
  for (int s = 0; s < 2; ++s)
    qf[s] = *(const bf16x8*)(qkv + (tokbase + qw + l16) * LDQKV + h * DKH + s * 32 + quad * 8);

  bf16x8 ones;
#pragma unroll
  for (int i = 0; i < 8; ++i) ones[i] = (__bf16)1.0f;

  f32x4 o[4], lacc;
  const f32x4 z = {0.f, 0.f, 0.f, 0.f};
#pragma unroll
  for (int t = 0; t < 4; ++t) o[t] = z;
  lacc = z;

  __bf16* pb = &pbuf[wave][0];
  const int swl = l16 & 7;   // K/V read-side swizzle key

  // prologue: stage key-tile 0 into buffer 0
  async_copy16(pKsrc, &sK[0][lo]);
  async_copy16(pKsrc + (size_t)8 * LDQKV, &sK[0][lo + 8 * 64]);
  async_copy16(pVsrc, &sV[0][lo]);
  async_copy16(pVsrc + (size_t)8 * SEQ, &sV[0][lo + 8 * 64]);

  for (int t0 = 0; t0 <= qb; ++t0) {
    const int cur = t0 & 1, nxt = cur ^ 1;
    __syncthreads();                 // tile t0 staged; prev reads of nxt done
    if (t0 < qb) {
      const size_t koff = (size_t)(t0 + 1) * 64;
      async_copy16(pKsrc + koff * LDQKV, &sK[nxt][lo]);
      async_copy16(pKsrc + (koff + 8) * LDQKV, &sK[nxt][lo + 8 * 64]);
      async_copy16(pVsrc + koff, &sV[nxt][lo]);
      async_copy16(pVsrc + (size_t)8 * SEQ + koff, &sV[nxt][lo + 8 * 64]);
    }
    const __bf16* K_ = &sK[cur][0];
    const __bf16* V_ = &sV[cur][0];

    // S^T = K Q^T : 4 row-tiles of 16 keys; lane holds keys ct*16+quad*4+r
    // for query l16 (C-layout with A=K, B=Q).
    f32x4 sacc[4];
#pragma unroll
    for (int ct = 0; ct < 4; ++ct) {
      bf16x8 k0 = *(const bf16x8*)(K_ + (ct * 16 + l16) * 64 + ((quad ^ swl) * 8));
      bf16x8 k1 = *(const bf16x8*)(K_ + (ct * 16 + l16) * 64 + (((4 + quad) ^ swl) * 8));
      sacc[ct] = MFMA_BF16(k0, qf[0], z);
      sacc[ct] = MFMA_BF16(k1, qf[1], sacc[ct]);
    }

    // P = exp2(S^T) -> packed bf16x4 -> per-wave LDS [q][k], XOR-swizzled
    // write granule g = ct*4+quad, swizzle key (q&7)<<1 (keeps 16B pairs).
#pragma unroll
    for (int ct = 0; ct < 4; ++ct) {
      bf16x4 p4;
      if (t0 < qb) {
#pragma unroll
        for (int r = 0; r < 4; ++r) p4[r] = (__bf16)exp2f(sacc[ct][r]);
      } else {
#pragma unroll
        for (int r = 0; r < 4; ++r) {
          float sv = (ct * 16 + quad * 4 + r <= wave * 16 + l16) ? sacc[ct][r] : -1e30f;
          p4[r] = (__bf16)exp2f(sv);
        }
      }
      *(bf16x4*)(pb + l16 * 64 + (((ct * 4 + quad) ^ (swl << 1)) * 4)) = p4;
    }
    // A-layout fragments: 16B granule-pair t = quad+4h, swizzled by q&7
    bf16x8 ap0 = *(const bf16x8*)(pb + l16 * 64 + ((quad ^ swl) * 8));
    bf16x8 ap1 = *(const bf16x8*)(pb + l16 * 64 + (((4 + quad) ^ swl) * 8));

    // l += P * 1 (row sums in C-layout: row quad*4+r = query — no shuffles)
    lacc = MFMA_BF16(ap0, ones, lacc);
    lacc = MFMA_BF16(ap1, ones, lacc);

    // O += P V : 4 dk-tiles
#pragma unroll
    for (int dt = 0; dt < 4; ++dt) {
      bf16x8 v0 = *(const bf16x8*)(V_ + (dt * 16 + l16) * 64 + ((quad ^ swl) * 8));
      bf16x8 v1 = *(const bf16x8*)(V_ + (dt * 16 + l16) * 64 + (((4 + quad) ^ swl) * 8));
      o[dt] = MFMA_BF16(ap0, v0, o[dt]);
      o[dt] = MFMA_BF16(ap1, v1, o[dt]);
    }
  }

  float linv[4];
#pragma unroll
  for (int r = 0; r < 4; ++r) linv[r] = 1.0f / lacc[r];

#pragma unroll
  for (int dt = 0; dt < 4; ++dt)
#pragma unroll
    for (int r = 0; r < 4; ++r)
      attn[(tokbase + qw + quad * 4 + r) * DMODEL + h * DKH + dt * 16 + l16] =
          (__bf16)(o[dt][r] * linv[r]);
}

// ---------------- launch ------------------------------------------------------
extern "C" void kernel_launch(void* const* d_in, const int* in_sizes, int n_in,
                              void* d_out, int out_size, void* d_ws, size_t ws_size,
                              hipStream_t stream) {
  const float* x  = (const float*)d_in[0];
  const float* wq = (const float*)d_in[1];
  const float* bq = (const float*)d_in[2];
  const float* wk = (const float*)d_in[3];
  const float* bk = (const float*)d_in[4];
  const float* wv = (const float*)d_in[5];
  const float* bv = (const float*)d_in[6];
  const float* wo = (const float*)d_in[7];
  const float* bo = (const float*)d_in[8];

  char* ws = (char*)d_ws;
  __bf16* xb    = (__bf16*)(ws + 0);
  __bf16* wqkv  = (__bf16*)(ws + 8388608);
  __bf16* wob   = (__bf16*)(ws + 14680064);
  float*  bcat  = (float*)(ws + 16777216);
  __bf16* qkv   = (__bf16*)(ws + 16789504);
  __bf16* vt    = (__bf16*)(ws + 41955328);
  __bf16* attn  = (__bf16*)(ws + 50343936);
  float*  out   = (float*)d_out;

  pack_kernel<<<1024, 256, 0, stream>>>(
      (const float4*)x, (const float4*)wq, (const float4*)wk, (const float4*)wv,
      (const float4*)wo, (const float4*)bq, (const float4*)bk, (const float4*)bv,
      (bf16x4*)xb, (bf16x4*)wqkv, (bf16x4*)wob, (float4*)bcat);

  // fused QKV projection: M=4096, N=3072, K=1024
  gemm_bias<128><<<dim3(32, 24), 256, 0, stream>>>(xb, wqkv, bcat, qkv, LDQKV, 1);

  vtrans_kernel<<<dim3(32, 32), 256, 0, stream>>>(qkv, vt);

  // flash attention: 1-D grid, balanced swizzle
  attn_kernel<<<1024, 256, 0, stream>>>(qkv, vt, attn);

  // output projection: M=4096, N=1024, K=1024, 128x64 tiles (512 blocks)
  gemm_bias<64><<<dim3(32, 16), 256, 0, stream>>>(attn, wob, bo, out, DMODEL, 0);
}

// Round 7
// 177.367 us; speedup vs baseline: 1.7519x; 1.0272x over previous
//
#include <hip/hip_runtime.h>
#include <cstdint>

// Problem constants: B=2, L=2048, D=1024, H=16, DK=64
#define SEQ     2048
#define DMODEL  1024
#define NHEAD   16
#define DKH     64
#define NTOK    4096      // B*L
#define LDQKV   3072      // qkv buffer row stride (q|k|v)

typedef __bf16 bf16x8 __attribute__((ext_vector_type(8)));
typedef __bf16 bf16x4 __attribute__((ext_vector_type(4)));
typedef float  f32x4  __attribute__((ext_vector_type(4)));

#define MFMA_BF16(a, b, c) __builtin_amdgcn_mfma_f32_16x16x32_bf16((a), (b), (c), 0, 0, 0)

// 0.125 * log2(e): folded into wq/bq at pack time. Softmax shift dropped
// entirely — exp2(s) scales O and l identically, cancels in O/l.
#define C2F 0.18033688f

// raw v_exp_f32 — libm exp2f is ~7 instrs (range/denorm handling) and was
// the round-6 VALU bottleneck (VALUBusy/MfmaUtil = 3.3).
__device__ inline float fast_exp2(float x) {
#if __has_builtin(__builtin_amdgcn_exp2f)
  return __builtin_amdgcn_exp2f(x);
#else
  return __expf(x * 0.69314718056f);
#endif
}

// async global->LDS copy, 16B per lane; LDS dest is wave-uniform base + lane*16
__device__ inline void async_copy16(const void* g, void* l) {
  __builtin_amdgcn_global_load_lds(
      reinterpret_cast<const __attribute__((address_space(1))) void*>(
          reinterpret_cast<uintptr_t>(g)),
      reinterpret_cast<__attribute__((address_space(3))) void*>(
          reinterpret_cast<uintptr_t>(l)),
      16, 0, 0);
}

__device__ inline bf16x4 cvt4(float4 v) {
  bf16x4 r;
  r[0] = (__bf16)v.x; r[1] = (__bf16)v.y; r[2] = (__bf16)v.z; r[3] = (__bf16)v.w;
  return r;
}

// ---------------- pack: fp32 -> bf16 casts + weight/bias concat ----------------
// wq and bq are pre-scaled by C2F (softmax scale folded into Q).
__global__ __launch_bounds__(256) void pack_kernel(
    const float4* __restrict__ x,
    const float4* __restrict__ wq, const float4* __restrict__ wk,
    const float4* __restrict__ wv, const float4* __restrict__ wo,
    const float4* __restrict__ bq, const float4* __restrict__ bk,
    const float4* __restrict__ bv,
    bf16x4* __restrict__ xb, bf16x4* __restrict__ wqkv,
    bf16x4* __restrict__ wob, float4* __restrict__ bcat)
{
  const int NX = NTOK * DMODEL / 4;       // 1048576 float4 groups of x
  const int NW = DMODEL * DMODEL / 4;     // 262144 per weight
  const int TOT = NX + 4 * NW + 3 * (DMODEL / 4);
  for (int g = blockIdx.x * 256 + threadIdx.x; g < TOT; g += gridDim.x * 256) {
    if (g < NX) {
      xb[g] = cvt4(x[g]);
    } else if (g < NX + 3 * NW) {
      int g2 = g - NX;
      const float4* s = (g2 < NW) ? wq : (g2 < 2 * NW ? wk : wv);
      float4 v = s[g2 & (NW - 1)];
      if (g2 < NW) { v.x *= C2F; v.y *= C2F; v.z *= C2F; v.w *= C2F; }
      wqkv[g2] = cvt4(v);
    } else if (g < NX + 4 * NW) {
      int g3 = g - NX - 3 * NW;
      wob[g3] = cvt4(wo[g3]);
    } else {
      int g4 = g - NX - 4 * NW;
      const float4* s = (g4 < 256) ? bq : (g4 < 512 ? bk : bv);
      float4 v = s[g4 & 255];
      if (g4 < 256) { v.x *= C2F; v.y *= C2F; v.z *= C2F; v.w *= C2F; }
      bcat[g4] = v;
    }
  }
}

// ---------------- GEMM: C[M,N] = A[M,K] * W[N,K]^T + bias, K=1024 -------------
// 128xBN tile (BN=128 or 64), double-buffered LDS staging.
template<int BN>
__global__ __launch_bounds__(256) void gemm_bias(
    const __bf16* __restrict__ A, const __bf16* __restrict__ W,
    const float* __restrict__ bias, void* __restrict__ C,
    int ldc, int out_bf16)
{
  constexpr int K = 1024;
  constexpr int JT = BN / 32;          // j-tiles per wave: 4 or 2
  __shared__ __bf16 sA[2][128 * 32];
  __shared__ __bf16 sB[2][BN * 32];
  const int tid  = threadIdx.x;
  const int wave = tid >> 6, lane = tid & 63;
  const int quad = lane >> 4, l16 = lane & 15;
  const size_t m0 = (size_t)blockIdx.x * 128;
  const size_t n0 = (size_t)blockIdx.y * BN;
  const int wm = (wave & 1) * 64, wn = (wave >> 1) * (BN / 2);

  const int g0 = wave * 2;
  const int sr = lane >> 2;          // row within 16-row group
  const int sc = (lane & 3) * 8;     // bf16 col offset within BK=32
  const __bf16* pa0 = A + (m0 + g0 * 16 + sr) * K + sc;
  const __bf16* pa1 = pa0 + 16 * K;
  const int brow = (BN == 128) ? g0 * 16 : wave * 16;
  const __bf16* pb0 = W + (n0 + brow + sr) * K + sc;
  const int lo  = g0 * 512;
  const int lob = (BN == 128) ? g0 * 512 : wave * 512;

  f32x4 acc[4][JT];
  const f32x4 z = {0.f, 0.f, 0.f, 0.f};
#pragma unroll
  for (int i = 0; i < 4; ++i)
#pragma unroll
    for (int j = 0; j < JT; ++j) acc[i][j] = z;

  // prologue: stage k0=0 into buffer 0
  async_copy16(pa0, &sA[0][lo]);
  async_copy16(pa1, &sA[0][lo + 512]);
  async_copy16(pb0, &sB[0][lob]);
  if (BN == 128) async_copy16(pb0 + 16 * K, &sB[0][lob + 512]);

  for (int k0 = 0; k0 < K; k0 += 32) {
    const int cur = (k0 >> 5) & 1, nxt = cur ^ 1;
    __syncthreads();                 // tile k0 staged; prev reads of nxt done
    if (k0 + 32 < K) {
      async_copy16(pa0 + k0 + 32, &sA[nxt][lo]);
      async_copy16(pa1 + k0 + 32, &sA[nxt][lo + 512]);
      async_copy16(pb0 + k0 + 32, &sB[nxt][lob]);
      if (BN == 128) async_copy16(pb0 + 16 * K + k0 + 32, &sB[nxt][lob + 512]);
    }

    bf16x8 af[4], bw[JT];
#pragma unroll
    for (int i = 0; i < 4; ++i)
      af[i] = *(const bf16x8*)(&sA[cur][(wm + i * 16 + l16) * 32 + quad * 8]);
#pragma unroll
    for (int j = 0; j < JT; ++j)
      bw[j] = *(const bf16x8*)(&sB[cur][(wn + j * 16 + l16) * 32 + quad * 8]);
#pragma unroll
    for (int i = 0; i < 4; ++i)
#pragma unroll
      for (int j = 0; j < JT; ++j)
        acc[i][j] = MFMA_BF16(af[i], bw[j], acc[i][j]);
  }

  float bi[JT];
#pragma unroll
  for (int j = 0; j < JT; ++j) bi[j] = bias[n0 + wn + j * 16 + l16];

#pragma unroll
  for (int i = 0; i < 4; ++i) {
#pragma unroll
    for (int j = 0; j < JT; ++j) {
#pragma unroll
      for (int r = 0; r < 4; ++r) {
        size_t row = m0 + wm + i * 16 + quad * 4 + r;
        size_t col = n0 + wn + j * 16 + l16;
        float v = acc[i][j][r] + bi[j];
        if (out_bf16) ((__bf16*)C)[row * ldc + col] = (__bf16)v;
        else          ((float*)C)[row * ldc + col] = v;
      }
    }
  }
}

// ---------------- V transpose: qkv v-slice (n, d) -> vt[(b,h,dk)][l] ----------
__global__ __launch_bounds__(256) void vtrans_kernel(
    const __bf16* __restrict__ qkv, __bf16* __restrict__ vt)
{
  __shared__ __bf16 t[64][66];
  const int tid = threadIdx.x;
  const int bh = blockIdx.x;           // b*16+h
  const int b = bh >> 4, h = bh & 15;
  const int l0 = blockIdx.y * 64;
  const int r4 = tid >> 6;             // 0..3
  const int c  = tid & 63;
#pragma unroll
  for (int rep = 0; rep < 16; ++rep) {
    int ll = rep * 4 + r4;
    t[ll][c] = qkv[(size_t)(b * SEQ + l0 + ll) * LDQKV + 2048 + h * DKH + c];
  }
  __syncthreads();
#pragma unroll
  for (int rep = 0; rep < 16; ++rep) {
    int dk = rep * 4 + r4;
    vt[(size_t)(bh * DKH + dk) * SEQ + l0 + c] = t[c][dk];
  }
}

// ---------------- MFMA flash attention (causal) -------------------------------
// Block = 4 waves x 16 queries; K/V^T 64x64 tiles double-buffered in LDS.
// S^T trick: compute K Q^T (swapped operands) so each lane holds 4 CONSECUTIVE
// keys for ONE query -> P repack is 4 packed ds_write_b64.
// No scale/shift in softmax (folded into wq; shift cancels in O/l).
// Row-sums l via MFMA with ones-B: lands in C-layout rows, zero shuffles.
// Balanced schedule: per CU the 4 round-robin blocks {w=0..3} get qb lengths
// {32-u, 1+u, 24+..., 9+...} (u XOR'd by (w>>1)<<3) summing to 66 exactly.
__global__ __launch_bounds__(256) void attn_kernel(
    const __bf16* __restrict__ qkv,   // [4096][3072]
    const __bf16* __restrict__ vt,    // [32*64][2048]
    __bf16* __restrict__ attn)        // [4096][1024]
{
  __shared__ __bf16 sK[2][64 * 64];   // [key][dk], granule-swizzled
  __shared__ __bf16 sV[2][64 * 64];   // [dk][key], granule-swizzled
  __shared__ __bf16 pbuf[4][16 * 64]; // per-wave P, [q][k] XOR-granule swizzle
  const int tid  = threadIdx.x;
  const int wave = tid >> 6, lane = tid & 63;
  const int quad = lane >> 4, l16 = lane & 15;
  const int id = blockIdx.x;
  const int u = (id >> 3) & 31, v = id & 7, w = id >> 8;
  const int bh = v * 4 + w;
  const int ue = u ^ ((w >> 1) << 3);         // temporal mix across the CU's 4 blocks
  const int qb = (w & 1) ? ue : 31 - ue;
  const int b = bh >> 4, h = bh & 15;
  const int q0 = qb * 64;
  const int qw = q0 + wave * 16;              // wave's first query row
  const size_t tokbase = (size_t)b * SEQ;

  // staging: lane l -> (row = l>>3, swizzled granule (l&7)^(l>>3))
  const int srow = lane >> 3;
  const int sgr  = (lane & 7) ^ srow;
  const __bf16* pKsrc = qkv + (tokbase + wave * 16 + srow) * LDQKV + 1024 + h * DKH + sgr * 8;
  const __bf16* pVsrc = vt + ((size_t)bh * DKH + wave * 16 + srow) * SEQ + sgr * 8;
  const int lo = wave * 16 * 64;              // wave's slab within buffer

  bf16x8 qf[2];
#pragma unroll
  for (int s = 0; s < 2; ++s)
    qf[s] = *(const bf16x8*)(qkv + (tokbase + qw + l16) * LDQKV + h * DKH + s * 32 + quad * 8);

  bf16x8 ones;
#pragma unroll
  for (int i = 0; i < 8; ++i) ones[i] = (__bf16)1.0f;

  f32x4 o[4], lacc;
  const f32x4 z = {0.f, 0.f, 0.f, 0.f};
#pragma unroll
  for (int t = 0; t < 4; ++t) o[t] = z;
  lacc = z;

  __bf16* pb = &pbuf[wave][0];
  const int swl = l16 & 7;   // K/V read-side swizzle key

  // prologue: stage key-tile 0 into buffer 0
  async_copy16(pKsrc, &sK[0][lo]);
  async_copy16(pKsrc + (size_t)8 * LDQKV, &sK[0][lo + 8 * 64]);
  async_copy16(pVsrc, &sV[0][lo]);
  async_copy16(pVsrc + (size_t)8 * SEQ, &sV[0][lo + 8 * 64]);

  for (int t0 = 0; t0 <= qb; ++t0) {
    const int cur = t0 & 1, nxt = cur ^ 1;
    __syncthreads();                 // tile t0 staged; prev reads of nxt done
    if (t0 < qb) {
      const size_t koff = (size_t)(t0 + 1) * 64;
      async_copy16(pKsrc + koff * LDQKV, &sK[nxt][lo]);
      async_copy16(pKsrc + (koff + 8) * LDQKV, &sK[nxt][lo + 8 * 64]);
      async_copy16(pVsrc + koff, &sV[nxt][lo]);
      async_copy16(pVsrc + (size_t)8 * SEQ + koff, &sV[nxt][lo + 8 * 64]);
    }
    const __bf16* K_ = &sK[cur][0];
    const __bf16* V_ = &sV[cur][0];

    // S^T = K Q^T : 4 row-tiles of 16 keys; lane holds keys ct*16+quad*4+r
    // for query l16 (C-layout with A=K, B=Q).
    f32x4 sacc[4];
#pragma unroll
    for (int ct = 0; ct < 4; ++ct) {
      bf16x8 k0 = *(const bf16x8*)(K_ + (ct * 16 + l16) * 64 + ((quad ^ swl) * 8));
      bf16x8 k1 = *(const bf16x8*)(K_ + (ct * 16 + l16) * 64 + (((4 + quad) ^ swl) * 8));
      sacc[ct] = MFMA_BF16(k0, qf[0], z);
      sacc[ct] = MFMA_BF16(k1, qf[1], sacc[ct]);
    }

    // P = exp2(S^T) -> packed bf16x4 -> per-wave LDS [q][k], XOR-swizzled
#pragma unroll
    for (int ct = 0; ct < 4; ++ct) {
      bf16x4 p4;
      if (t0 < qb) {
#pragma unroll
        for (int r = 0; r < 4; ++r) p4[r] = (__bf16)fast_exp2(sacc[ct][r]);
      } else {
#pragma unroll
        for (int r = 0; r < 4; ++r) {
          float sv = (ct * 16 + quad * 4 + r <= wave * 16 + l16) ? sacc[ct][r] : -1e30f;
          p4[r] = (__bf16)fast_exp2(sv);
        }
      }
      *(bf16x4*)(pb + l16 * 64 + (((ct * 4 + quad) ^ (swl << 1)) * 4)) = p4;
    }
    // A-layout fragments: 16B granule-pair t = quad+4h, swizzled by q&7
    bf16x8 ap0 = *(const bf16x8*)(pb + l16 * 64 + ((quad ^ swl) * 8));
    bf16x8 ap1 = *(const bf16x8*)(pb + l16 * 64 + (((4 + quad) ^ swl) * 8));

    // l += P * 1 (row sums in C-layout: row quad*4+r = query — no shuffles)
    lacc = MFMA_BF16(ap0, ones, lacc);
    lacc = MFMA_BF16(ap1, ones, lacc);

    // O += P V : 4 dk-tiles
#pragma unroll
    for (int dt = 0; dt < 4; ++dt) {
      bf16x8 v0 = *(const bf16x8*)(V_ + (dt * 16 + l16) * 64 + ((quad ^ swl) * 8));
      bf16x8 v1 = *(const bf16x8*)(V_ + (dt * 16 + l16) * 64 + (((4 + quad) ^ swl) * 8));
      o[dt] = MFMA_BF16(ap0, v0, o[dt]);
      o[dt] = MFMA_BF16(ap1, v1, o[dt]);
    }
  }

  float linv[4];
#pragma unroll
  for (int r = 0; r < 4; ++r) linv[r] = 1.0f / lacc[r];

#pragma unroll
  for (int dt = 0; dt < 4; ++dt)
#pragma unroll
    for (int r = 0; r < 4; ++r)
      attn[(tokbase + qw + quad * 4 + r) * DMODEL + h * DKH + dt * 16 + l16] =
          (__bf16)(o[dt][r] * linv[r]);
}

// ---------------- launch ------------------------------------------------------
extern "C" void kernel_launch(void* const* d_in, const int* in_sizes, int n_in,
                              void* d_out, int out_size, void* d_ws, size_t ws_size,
                              hipStream_t stream) {
  const float* x  = (const float*)d_in[0];
  const float* wq = (const float*)d_in[1];
  const float* bq = (const float*)d_in[2];
  const float* wk = (const float*)d_in[3];
  const float* bk = (const float*)d_in[4];
  const float* wv = (const float*)d_in[5];
  const float* bv = (const float*)d_in[6];
  const float* wo = (const float*)d_in[7];
  const float* bo = (const float*)d_in[8];

  char* ws = (char*)d_ws;
  __bf16* xb    = (__bf16*)(ws + 0);
  __bf16* wqkv  = (__bf16*)(ws + 8388608);
  __bf16* wob   = (__bf16*)(ws + 14680064);
  float*  bcat  = (float*)(ws + 16777216);
  __bf16* qkv   = (__bf16*)(ws + 16789504);
  __bf16* vt    = (__bf16*)(ws + 41955328);
  __bf16* attn  = (__bf16*)(ws + 50343936);
  float*  out   = (float*)d_out;

  pack_kernel<<<1024, 256, 0, stream>>>(
      (const float4*)x, (const float4*)wq, (const float4*)wk, (const float4*)wv,
      (const float4*)wo, (const float4*)bq, (const float4*)bk, (const float4*)bv,
      (bf16x4*)xb, (bf16x4*)wqkv, (bf16x4*)wob, (float4*)bcat);

  // fused QKV projection: M=4096, N=3072, K=1024
  gemm_bias<128><<<dim3(32, 24), 256, 0, stream>>>(xb, wqkv, bcat, qkv, LDQKV, 1);

  vtrans_kernel<<<dim3(32, 32), 256, 0, stream>>>(qkv, vt);

  // flash attention: 1-D grid, balanced swizzle
  attn_kernel<<<1024, 256, 0, stream>>>(qkv, vt, attn);

  // output projection: M=4096, N=1024, K=1024, 128x64 tiles (512 blocks)
  gemm_bias<64><<<dim3(32, 16), 256, 0, stream>>>(attn, wob, bo, out, DMODEL, 0);
}